// Round 5
// baseline (2364.312 us; speedup 1.0000x reference)
//
#include <hip/hip_runtime.h>

// ---------------------------------------------------------------------------
// Motion_Grid: PE(sin/cos @ 3 freqs) -> 6 trilinear samples (3 grids) -> MLP
// Round 5: = round 4 (parallel scan + fdot2 MLP) with the cvt_pkrtz type fix.
// ---------------------------------------------------------------------------

#define NBINS 32768   // 32^3 buckets over raw x in [0,1)^3; 128 blocks x 256
#define NXCD 8

typedef _Float16 f16x2 __attribute__((ext_vector_type(2)));

__device__ __forceinline__ f16x2 pkrtz(float a, float b) {
    return __builtin_bit_cast(f16x2, __builtin_amdgcn_cvt_pkrtz(a, b));
}

#if defined(__has_builtin)
#if __has_builtin(__builtin_amdgcn_fdot2)
#define HAS_FDOT2 1
#endif
#endif

// Pack grid + noise into (D,H,W,C) layout so one corner-pair = contiguous bytes.
template<int C>
__global__ __launch_bounds__(256)
void pack_grid_k(const float* __restrict__ g, const float* __restrict__ nz,
                 float* __restrict__ out, int nvox) {
    int v = blockIdx.x * 256 + threadIdx.x;
    if (v >= nvox) return;
    float vals[C];
#pragma unroll
    for (int c = 0; c < C; ++c) vals[c] = g[c * nvox + v] + nz[c * nvox + v];
#pragma unroll
    for (int c = 0; c < C; ++c) out[v * C + c] = vals[c];
}

// Pack w1 (64x20) and w2 (7x64) into f16-pair (uint32) tables:
//   w1h[j*10+p] = pack(w1[j][2p], w1[j][2p+1])   (640 uints)
//   w2h[o*32+p] = pack(w2[o][2p], w2[o][2p+1])   (224 uints)
__global__ __launch_bounds__(1024)
void pack_w_k(const float* __restrict__ w1, const float* __restrict__ w2,
              unsigned* __restrict__ w1h, unsigned* __restrict__ w2h) {
    int i = threadIdx.x;
    if (i < 640) {
        int j = i / 10, p = i % 10;
        w1h[i] = __builtin_bit_cast(unsigned, pkrtz(w1[j * 20 + 2 * p], w1[j * 20 + 2 * p + 1]));
    } else if (i < 640 + 224) {
        int k = i - 640;
        int o = k / 32, p = k % 32;
        w2h[k] = __builtin_bit_cast(unsigned, pkrtz(w2[o * 64 + 2 * p], w2[o * 64 + 2 * p + 1]));
    }
}

__device__ __forceinline__ int bin_of(float xv, float yv, float zv) {
    int qx = min(max((int)(xv * 32.f), 0), 31);
    int qy = min(max((int)(yv * 32.f), 0), 31);
    int qz = min(max((int)(zv * 32.f), 0), 31);
    return (qz << 10) | (qy << 5) | qx;
}

__global__ __launch_bounds__(256)
void hist_k(const float* __restrict__ x, int* __restrict__ hist, int npts) {
    int p = blockIdx.x * 256 + threadIdx.x;
    if (p >= npts) return;
    atomicAdd(&hist[bin_of(x[3 * p], x[3 * p + 1], x[3 * p + 2])], 1);
}

// --- 3-stage parallel exclusive scan over NBINS = 128*256 -------------------
__global__ __launch_bounds__(256)
void scan_part_k(const int* __restrict__ hist, int* __restrict__ partials) {
    __shared__ int red[4];
    int t = threadIdx.x, b = blockIdx.x;
    int v = hist[b * 256 + t];
#pragma unroll
    for (int d = 1; d < 64; d <<= 1) v += __shfl_xor(v, d);
    if ((t & 63) == 0) red[t >> 6] = v;
    __syncthreads();
    if (t == 0) partials[b] = red[0] + red[1] + red[2] + red[3];
}

__global__ __launch_bounds__(128)
void scan_top_k(const int* __restrict__ partials, int* __restrict__ top) {
    __shared__ int sh[128];
    int t = threadIdx.x;
    int v = partials[t];
    sh[t] = v;
    __syncthreads();
    for (int d = 1; d < 128; d <<= 1) {
        int add = (t >= d) ? sh[t - d] : 0;
        __syncthreads();
        sh[t] += add;
        __syncthreads();
    }
    top[t] = sh[t] - v;  // exclusive
}

__global__ __launch_bounds__(256)
void scan_down_k(const int* __restrict__ hist, const int* __restrict__ top,
                 int* __restrict__ offs) {
    __shared__ int sh[256];
    int t = threadIdx.x, b = blockIdx.x;
    int v = hist[b * 256 + t];
    sh[t] = v;
    __syncthreads();
    for (int d = 1; d < 256; d <<= 1) {
        int add = (t >= d) ? sh[t - d] : 0;
        __syncthreads();
        sh[t] += add;
        __syncthreads();
    }
    offs[b * 256 + t] = sh[t] - v + top[b];
}
// ----------------------------------------------------------------------------

__global__ __launch_bounds__(256)
void scatter_k(const float* __restrict__ x, int* __restrict__ offs,
               float4* __restrict__ sorted, int npts) {
    int p = blockIdx.x * 256 + threadIdx.x;
    if (p >= npts) return;
    float xv = x[3 * p], yv = x[3 * p + 1], zv = x[3 * p + 2];
    int pos = atomicAdd(&offs[bin_of(xv, yv, zv)], 1);
    float4 v; v.x = xv; v.y = yv; v.z = zv; v.w = __int_as_float(p);
    sorted[pos] = v;
}

// Trilinear sample, border-zero semantics, channel-innermost vol, fused x-pair.
template<int C, int S>
__device__ __forceinline__ void trilerp(const float* __restrict__ vol,
                                        float cx, float cy, float cz,
                                        float* __restrict__ f) {
    const float hs = (float)S * 0.5f;
    float gx = fmaf(cx, hs, hs - 0.5f);
    float gy = fmaf(cy, hs, hs - 0.5f);
    float gz = fmaf(cz, hs, hs - 0.5f);
    float fx = floorf(gx), fy = floorf(gy), fz = floorf(gz);
    float tx = gx - fx, ty = gy - fy, tz = gz - fz;
    int x0 = (int)fx, y0 = (int)fy, z0 = (int)fz;
    float wx0 = (1.f - tx) * ((x0 >= 0)    ? 1.f : 0.f);
    float wx1 = tx         * ((x0 + 1 < S) ? 1.f : 0.f);
    float wy0 = (1.f - ty) * ((y0 >= 0)    ? 1.f : 0.f);
    float wy1 = ty         * ((y0 + 1 < S) ? 1.f : 0.f);
    float wz0 = (1.f - tz) * ((z0 >= 0)    ? 1.f : 0.f);
    float wz1 = tz         * ((z0 + 1 < S) ? 1.f : 0.f);

    const int xb = max(x0, 0);
    const bool xlo_ok = (x0 >= 0);
    int ys[2], zs[2];
    ys[0] = max(y0, 0); ys[1] = min(y0 + 1, S - 1);
    zs[0] = max(z0, 0); zs[1] = min(z0 + 1, S - 1);
    float wys[2] = {wy0, wy1}, wzs[2] = {wz0, wz1};

#pragma unroll
    for (int dz = 0; dz < 2; ++dz) {
#pragma unroll
        for (int dy = 0; dy < 2; ++dy) {
            const float wzy = wzs[dz] * wys[dy];
            const float w0 = wzy * wx0, w1 = wzy * wx1;
            const float* p = vol + ((zs[dz] * S + ys[dy]) * S + xb) * C;
            if (C == 4) {
                float4 lo = *reinterpret_cast<const float4*>(p);
                float4 hi = *reinterpret_cast<const float4*>(p + 4);
                if (!xlo_ok) hi = lo;
                f[0] = fmaf(w0, lo.x, f[0]); f[0] = fmaf(w1, hi.x, f[0]);
                f[1] = fmaf(w0, lo.y, f[1]); f[1] = fmaf(w1, hi.y, f[1]);
                f[2] = fmaf(w0, lo.z, f[2]); f[2] = fmaf(w1, hi.z, f[2]);
                f[3] = fmaf(w0, lo.w, f[3]); f[3] = fmaf(w1, hi.w, f[3]);
            } else {
                float4 v = *reinterpret_cast<const float4*>(p);
                float hx = xlo_ok ? v.z : v.x;
                float hy = xlo_ok ? v.w : v.y;
                f[0] = fmaf(w0, v.x, f[0]); f[0] = fmaf(w1, hx, f[0]);
                f[1] = fmaf(w0, v.y, f[1]); f[1] = fmaf(w1, hy, f[1]);
            }
        }
    }
}

__global__ __launch_bounds__(256)
void motion_grid_main(const float4* __restrict__ sorted,
                      const float* __restrict__ xraw,
                      const float* __restrict__ g0,
                      const float* __restrict__ g1,
                      const float* __restrict__ g2,
                      const unsigned* __restrict__ w1h,
                      const float* __restrict__ b1,
                      const unsigned* __restrict__ w2h,
                      const float* __restrict__ b2,
                      float* __restrict__ out, int npts, int sortedMode,
                      int nblk) {
    // Chunked XCD swizzle: each XCD gets a contiguous run of sorted blocks.
    int bid = blockIdx.x;
    if ((nblk & (NXCD - 1)) == 0) {
        int cpx = nblk / NXCD;
        bid = (bid % NXCD) * cpx + bid / NXCD;
    }
    const int p = bid * 256 + threadIdx.x;
    if (p >= npts) return;

    float xv, yv, zv;
    int orig;
    if (sortedMode) {
        float4 sp = sorted[p];
        xv = sp.x; yv = sp.y; zv = sp.z; orig = __float_as_int(sp.w);
    } else {
        xv = xraw[3 * p]; yv = xraw[3 * p + 1]; zv = xraw[3 * p + 2];
        orig = p;
    }

    // hw trig takes revolutions: sin(pi t)=hw(t/2), sin(2pi t)=hw(t), sin(4pi t)=hw(2t)
    float s1[3], c1[3], s2[3], c2[3], s4[3], c4[3];
    {
        const float xs[3] = {xv, yv, zv};
#pragma unroll
        for (int d = 0; d < 3; ++d) {
            s1[d] = __builtin_amdgcn_sinf(0.5f * xs[d]);
            c1[d] = __builtin_amdgcn_cosf(0.5f * xs[d]);
            s2[d] = __builtin_amdgcn_sinf(xs[d]);
            c2[d] = __builtin_amdgcn_cosf(xs[d]);
            s4[d] = __builtin_amdgcn_sinf(2.0f * xs[d]);
            c4[d] = __builtin_amdgcn_cosf(2.0f * xs[d]);
        }
    }

    float f[20];
#pragma unroll
    for (int i = 0; i < 20; ++i) f[i] = 0.f;

    trilerp<4, 32>(g0, s1[0], s1[1], s1[2], f + 0);
    trilerp<4, 32>(g0, c1[0], c1[1], c1[2], f + 4);
    trilerp<4, 64>(g1, s2[0], s2[1], s2[2], f + 8);
    trilerp<4, 64>(g1, c2[0], c2[1], c2[2], f + 12);
    trilerp<2, 128>(g2, s4[0], s4[1], s4[2], f + 16);
    trilerp<2, 128>(g2, c4[0], c4[1], c4[2], f + 18);

    float acc[7];
#pragma unroll
    for (int o = 0; o < 7; ++o) acc[o] = b2[o];

#ifdef HAS_FDOT2
    // f16-pair dot-product MLP: v_dot2_f32_f16 = 2 MACs / VALU instr, f32 acc.
    f16x2 fh[10];
#pragma unroll
    for (int i = 0; i < 10; ++i) fh[i] = pkrtz(f[2 * i], f[2 * i + 1]);

    f16x2 hh[32];
#pragma unroll 2
    for (int j = 0; j < 64; j += 2) {
        float s0 = b1[j], s1v = b1[j + 1];
#pragma unroll
        for (int q = 0; q < 10; ++q) {
            f16x2 wa = __builtin_bit_cast(f16x2, w1h[j * 10 + q]);
            f16x2 wb = __builtin_bit_cast(f16x2, w1h[(j + 1) * 10 + q]);
            s0  = __builtin_amdgcn_fdot2(fh[q], wa, s0, false);
            s1v = __builtin_amdgcn_fdot2(fh[q], wb, s1v, false);
        }
        s0  = fmaxf(s0, 0.01f * s0);
        s1v = fmaxf(s1v, 0.01f * s1v);
        hh[j >> 1] = pkrtz(s0, s1v);
    }

#pragma unroll 4
    for (int q = 0; q < 32; ++q) {
        f16x2 hv = hh[q];
#pragma unroll
        for (int o = 0; o < 7; ++o)
            acc[o] = __builtin_amdgcn_fdot2(hv, __builtin_bit_cast(f16x2, w2h[o * 32 + q]), acc[o], false);
    }
#else
    // Fallback: f32 math on the same packed-f16 weights.
#pragma unroll 2
    for (int j = 0; j < 64; ++j) {
        float s = b1[j];
#pragma unroll
        for (int q = 0; q < 10; ++q) {
            f16x2 w = __builtin_bit_cast(f16x2, w1h[j * 10 + q]);
            s = fmaf(f[2 * q], (float)w[0], s);
            s = fmaf(f[2 * q + 1], (float)w[1], s);
        }
        float h = fmaxf(s, 0.01f * s);
#pragma unroll
        for (int o = 0; o < 7; ++o) {
            f16x2 w = __builtin_bit_cast(f16x2, w2h[o * 32 + (j >> 1)]);
            acc[o] = fmaf(h, (float)w[j & 1], acc[o]);
        }
    }
#endif

    float* op = out + (size_t)orig * 7;
#pragma unroll
    for (int o = 0; o < 7; ++o) op[o] = acc[o];
}

extern "C" void kernel_launch(void* const* d_in, const int* in_sizes, int n_in,
                              void* d_out, int out_size, void* d_ws, size_t ws_size,
                              hipStream_t stream) {
    const float* x  = (const float*)d_in[0];
    const float* g0 = (const float*)d_in[1];
    const float* g1 = (const float*)d_in[2];
    const float* g2 = (const float*)d_in[3];
    const float* n0 = (const float*)d_in[4];
    const float* n1 = (const float*)d_in[5];
    const float* n2 = (const float*)d_in[6];
    const float* w1 = (const float*)d_in[7];
    const float* b1 = (const float*)d_in[8];
    const float* w2 = (const float*)d_in[9];
    const float* b2 = (const float*)d_in[10];
    float* out = (float*)d_out;

    const int npts = in_sizes[0] / 3;

    char* ws = (char*)d_ws;
    size_t cur = 0;
    auto alloc = [&](size_t bytes) {
        char* p = ws + cur;
        cur = (cur + bytes + 255) & ~(size_t)255;
        return p;
    };
    float*    p0       = (float*)   alloc(32768u   * 4 * 4 + 64);
    float*    p1       = (float*)   alloc(262144u  * 4 * 4 + 64);
    float*    p2       = (float*)   alloc(2097152u * 2 * 4 + 64);
    unsigned* w1h      = (unsigned*)alloc(640 * 4);
    unsigned* w2h      = (unsigned*)alloc(224 * 4);
    int*      hist     = (int*)     alloc(NBINS * 4);
    int*      offs     = (int*)     alloc(NBINS * 4);
    int*      partials = (int*)     alloc(128 * 4);
    int*      top      = (int*)     alloc(128 * 4);
    float4*   sorted   = (float4*)  alloc((size_t)npts * 16);
    const int useSorted = (ws_size >= cur) ? 1 : 0;

    pack_grid_k<4><<<(32768 + 255) / 256, 256, 0, stream>>>(g0, n0, p0, 32768);
    pack_grid_k<4><<<(262144 + 255) / 256, 256, 0, stream>>>(g1, n1, p1, 262144);
    pack_grid_k<2><<<(2097152 + 255) / 256, 256, 0, stream>>>(g2, n2, p2, 2097152);
    pack_w_k<<<1, 1024, 0, stream>>>(w1, w2, w1h, w2h);

    const int nblk = (npts + 255) / 256;
    if (useSorted) {
        (void)hipMemsetAsync(hist, 0, NBINS * 4, stream);
        hist_k<<<nblk, 256, 0, stream>>>(x, hist, npts);
        scan_part_k<<<128, 256, 0, stream>>>(hist, partials);
        scan_top_k<<<1, 128, 0, stream>>>(partials, top);
        scan_down_k<<<128, 256, 0, stream>>>(hist, top, offs);
        scatter_k<<<nblk, 256, 0, stream>>>(x, offs, sorted, npts);
    }

    motion_grid_main<<<nblk, 256, 0, stream>>>(
        sorted, x, p0, p1, p2, w1h, b1, w2h, b2, out, npts, useSorted, nblk);
}

// Round 6
// 446.284 us; speedup vs baseline: 5.2978x; 5.2978x over previous
//
#include <hip/hip_runtime.h>

// ---------------------------------------------------------------------------
// Motion_Grid: PE(sin/cos @ 3 freqs) -> 6 trilinear samples (3 grids) -> MLP
// Round 6: fix round-5 scratch bug (FULL unroll of fdot2 MLP loops — rule #20:
//          runtime-indexed local arrays spill to scratch), fuse prep kernels.
// ---------------------------------------------------------------------------

#define NBINS 32768   // 32^3 buckets over raw x in [0,1)^3
#define NXCD 8

typedef _Float16 f16x2 __attribute__((ext_vector_type(2)));

__device__ __forceinline__ f16x2 pkrtz(float a, float b) {
    return __builtin_bit_cast(f16x2, __builtin_amdgcn_cvt_pkrtz(a, b));
}

__device__ __forceinline__ int bin_of(float xv, float yv, float zv) {
    int qx = min(max((int)(xv * 32.f), 0), 31);
    int qy = min(max((int)(yv * 32.f), 0), 31);
    int qz = min(max((int)(zv * 32.f), 0), 31);
    return (qz << 10) | (qy << 5) | qx;
}

// ---- Fused prep: pack g2 | hist | pack g1 | pack g0 | pack weights ---------
// Block ranges (256 threads each):
//   [0, 8192)            : pack grid2 (2 ch, 128^3)
//   [8192, 16384)        : histogram of x bins
//   [16384, 17408)       : pack grid1 (4 ch, 64^3)
//   [17408, 17536)       : pack grid0 (4 ch, 32^3)
//   [17536, 17540)       : pack w1/w2 -> f16-pair tables
#define PREP_BLOCKS 17540

__global__ __launch_bounds__(256)
void prep_k(const float* __restrict__ x,
            const float* __restrict__ g0, const float* __restrict__ n0,
            const float* __restrict__ g1, const float* __restrict__ n1,
            const float* __restrict__ g2, const float* __restrict__ n2,
            const float* __restrict__ w1, const float* __restrict__ w2,
            float* __restrict__ p0, float* __restrict__ p1, float* __restrict__ p2,
            unsigned* __restrict__ w1h, unsigned* __restrict__ w2h,
            int* __restrict__ hist, int npts) {
    const int b = blockIdx.x, t = threadIdx.x;
    if (b < 8192) {                      // pack grid2: nvox = 2097152, C=2
        int v = b * 256 + t;
        float a = g2[v] + n2[v];
        float c = g2[2097152 + v] + n2[2097152 + v];
        float2* o = reinterpret_cast<float2*>(p2);
        o[v] = make_float2(a, c);
    } else if (b < 16384) {              // histogram (8192 blocks covers 2M pts)
        int p = (b - 8192) * 256 + t;
        if (p < npts)
            atomicAdd(&hist[bin_of(x[3 * p], x[3 * p + 1], x[3 * p + 2])], 1);
    } else if (b < 17408) {              // pack grid1: nvox = 262144, C=4
        int v = (b - 16384) * 256 + t;
        float4 r;
        r.x = g1[v] + n1[v];
        r.y = g1[262144 + v] + n1[262144 + v];
        r.z = g1[524288 + v] + n1[524288 + v];
        r.w = g1[786432 + v] + n1[786432 + v];
        reinterpret_cast<float4*>(p1)[v] = r;
    } else if (b < 17536) {              // pack grid0: nvox = 32768, C=4
        int v = (b - 17408) * 256 + t;
        float4 r;
        r.x = g0[v] + n0[v];
        r.y = g0[32768 + v] + n0[32768 + v];
        r.z = g0[65536 + v] + n0[65536 + v];
        r.w = g0[98304 + v] + n0[98304 + v];
        reinterpret_cast<float4*>(p0)[v] = r;
    } else {                             // pack weights: 640 + 224 items
        int i = (b - 17536) * 256 + t;
        if (i < 640) {
            int j = i / 10, q = i % 10;
            w1h[i] = __builtin_bit_cast(unsigned, pkrtz(w1[j * 20 + 2 * q], w1[j * 20 + 2 * q + 1]));
        } else if (i < 864) {
            int k = i - 640;
            int o = k / 32, q = k % 32;
            w2h[k] = __builtin_bit_cast(unsigned, pkrtz(w2[o * 64 + 2 * q], w2[o * 64 + 2 * q + 1]));
        }
    }
}

// --- 3-stage parallel exclusive scan over NBINS = 128*256 -------------------
__global__ __launch_bounds__(256)
void scan_part_k(const int* __restrict__ hist, int* __restrict__ partials) {
    __shared__ int red[4];
    int t = threadIdx.x, b = blockIdx.x;
    int v = hist[b * 256 + t];
#pragma unroll
    for (int d = 1; d < 64; d <<= 1) v += __shfl_xor(v, d);
    if ((t & 63) == 0) red[t >> 6] = v;
    __syncthreads();
    if (t == 0) partials[b] = red[0] + red[1] + red[2] + red[3];
}

__global__ __launch_bounds__(128)
void scan_top_k(const int* __restrict__ partials, int* __restrict__ top) {
    __shared__ int sh[128];
    int t = threadIdx.x;
    int v = partials[t];
    sh[t] = v;
    __syncthreads();
    for (int d = 1; d < 128; d <<= 1) {
        int add = (t >= d) ? sh[t - d] : 0;
        __syncthreads();
        sh[t] += add;
        __syncthreads();
    }
    top[t] = sh[t] - v;  // exclusive
}

__global__ __launch_bounds__(256)
void scan_down_k(const int* __restrict__ hist, const int* __restrict__ top,
                 int* __restrict__ offs) {
    __shared__ int sh[256];
    int t = threadIdx.x, b = blockIdx.x;
    int v = hist[b * 256 + t];
    sh[t] = v;
    __syncthreads();
    for (int d = 1; d < 256; d <<= 1) {
        int add = (t >= d) ? sh[t - d] : 0;
        __syncthreads();
        sh[t] += add;
        __syncthreads();
    }
    offs[b * 256 + t] = sh[t] - v + top[b];
}
// ----------------------------------------------------------------------------

__global__ __launch_bounds__(256)
void scatter_k(const float* __restrict__ x, int* __restrict__ offs,
               float4* __restrict__ sorted, int npts) {
    int p = blockIdx.x * 256 + threadIdx.x;
    if (p >= npts) return;
    float xv = x[3 * p], yv = x[3 * p + 1], zv = x[3 * p + 2];
    int pos = atomicAdd(&offs[bin_of(xv, yv, zv)], 1);
    float4 v; v.x = xv; v.y = yv; v.z = zv; v.w = __int_as_float(p);
    sorted[pos] = v;
}

// Trilinear sample, border-zero semantics, channel-innermost vol, fused x-pair.
template<int C, int S>
__device__ __forceinline__ void trilerp(const float* __restrict__ vol,
                                        float cx, float cy, float cz,
                                        float* __restrict__ f) {
    const float hs = (float)S * 0.5f;
    float gx = fmaf(cx, hs, hs - 0.5f);
    float gy = fmaf(cy, hs, hs - 0.5f);
    float gz = fmaf(cz, hs, hs - 0.5f);
    float fx = floorf(gx), fy = floorf(gy), fz = floorf(gz);
    float tx = gx - fx, ty = gy - fy, tz = gz - fz;
    int x0 = (int)fx, y0 = (int)fy, z0 = (int)fz;
    float wx0 = (1.f - tx) * ((x0 >= 0)    ? 1.f : 0.f);
    float wx1 = tx         * ((x0 + 1 < S) ? 1.f : 0.f);
    float wy0 = (1.f - ty) * ((y0 >= 0)    ? 1.f : 0.f);
    float wy1 = ty         * ((y0 + 1 < S) ? 1.f : 0.f);
    float wz0 = (1.f - tz) * ((z0 >= 0)    ? 1.f : 0.f);
    float wz1 = tz         * ((z0 + 1 < S) ? 1.f : 0.f);

    const int xb = max(x0, 0);
    const bool xlo_ok = (x0 >= 0);
    int ys[2], zs[2];
    ys[0] = max(y0, 0); ys[1] = min(y0 + 1, S - 1);
    zs[0] = max(z0, 0); zs[1] = min(z0 + 1, S - 1);
    float wys[2] = {wy0, wy1}, wzs[2] = {wz0, wz1};

#pragma unroll
    for (int dz = 0; dz < 2; ++dz) {
#pragma unroll
        for (int dy = 0; dy < 2; ++dy) {
            const float wzy = wzs[dz] * wys[dy];
            const float w0 = wzy * wx0, w1 = wzy * wx1;
            const float* p = vol + ((zs[dz] * S + ys[dy]) * S + xb) * C;
            if (C == 4) {
                float4 lo = *reinterpret_cast<const float4*>(p);
                float4 hi = *reinterpret_cast<const float4*>(p + 4);
                if (!xlo_ok) hi = lo;
                f[0] = fmaf(w0, lo.x, f[0]); f[0] = fmaf(w1, hi.x, f[0]);
                f[1] = fmaf(w0, lo.y, f[1]); f[1] = fmaf(w1, hi.y, f[1]);
                f[2] = fmaf(w0, lo.z, f[2]); f[2] = fmaf(w1, hi.z, f[2]);
                f[3] = fmaf(w0, lo.w, f[3]); f[3] = fmaf(w1, hi.w, f[3]);
            } else {
                float4 v = *reinterpret_cast<const float4*>(p);
                float hx = xlo_ok ? v.z : v.x;
                float hy = xlo_ok ? v.w : v.y;
                f[0] = fmaf(w0, v.x, f[0]); f[0] = fmaf(w1, hx, f[0]);
                f[1] = fmaf(w0, v.y, f[1]); f[1] = fmaf(w1, hy, f[1]);
            }
        }
    }
}

__global__ __launch_bounds__(256)
void motion_grid_main(const float4* __restrict__ sorted,
                      const float* __restrict__ xraw,
                      const float* __restrict__ g0,
                      const float* __restrict__ g1,
                      const float* __restrict__ g2,
                      const unsigned* __restrict__ w1h,
                      const float* __restrict__ b1,
                      const unsigned* __restrict__ w2h,
                      const float* __restrict__ b2,
                      float* __restrict__ out, int npts, int sortedMode,
                      int nblk) {
    // Chunked XCD swizzle: each XCD gets a contiguous run of sorted blocks.
    int bid = blockIdx.x;
    if ((nblk & (NXCD - 1)) == 0) {
        int cpx = nblk / NXCD;
        bid = (bid % NXCD) * cpx + bid / NXCD;
    }
    const int p = bid * 256 + threadIdx.x;
    if (p >= npts) return;

    float xv, yv, zv;
    int orig;
    if (sortedMode) {
        float4 sp = sorted[p];
        xv = sp.x; yv = sp.y; zv = sp.z; orig = __float_as_int(sp.w);
    } else {
        xv = xraw[3 * p]; yv = xraw[3 * p + 1]; zv = xraw[3 * p + 2];
        orig = p;
    }

    // hw trig takes revolutions: sin(pi t)=hw(t/2), sin(2pi t)=hw(t), sin(4pi t)=hw(2t)
    float s1[3], c1[3], s2[3], c2[3], s4[3], c4[3];
    {
        const float xs[3] = {xv, yv, zv};
#pragma unroll
        for (int d = 0; d < 3; ++d) {
            s1[d] = __builtin_amdgcn_sinf(0.5f * xs[d]);
            c1[d] = __builtin_amdgcn_cosf(0.5f * xs[d]);
            s2[d] = __builtin_amdgcn_sinf(xs[d]);
            c2[d] = __builtin_amdgcn_cosf(xs[d]);
            s4[d] = __builtin_amdgcn_sinf(2.0f * xs[d]);
            c4[d] = __builtin_amdgcn_cosf(2.0f * xs[d]);
        }
    }

    float f[20];
#pragma unroll
    for (int i = 0; i < 20; ++i) f[i] = 0.f;

    trilerp<4, 32>(g0, s1[0], s1[1], s1[2], f + 0);
    trilerp<4, 32>(g0, c1[0], c1[1], c1[2], f + 4);
    trilerp<4, 64>(g1, s2[0], s2[1], s2[2], f + 8);
    trilerp<4, 64>(g1, c2[0], c2[1], c2[2], f + 12);
    trilerp<2, 128>(g2, s4[0], s4[1], s4[2], f + 16);
    trilerp<2, 128>(g2, c4[0], c4[1], c4[2], f + 18);

    float acc[7];
#pragma unroll
    for (int o = 0; o < 7; ++o) acc[o] = b2[o];

    // f16-pair dot-product MLP: v_dot2_f32_f16 = 2 MACs / VALU instr, f32 acc.
    // ALL loops fully unrolled -> every local-array index is compile-time
    // (rule #20: runtime-indexed ext_vector arrays spill to scratch).
    f16x2 fh[10];
#pragma unroll
    for (int i = 0; i < 10; ++i) fh[i] = pkrtz(f[2 * i], f[2 * i + 1]);

    f16x2 hh[32];
#pragma unroll
    for (int j = 0; j < 64; j += 2) {
        float s0 = b1[j], s1v = b1[j + 1];
#pragma unroll
        for (int q = 0; q < 10; ++q) {
            f16x2 wa = __builtin_bit_cast(f16x2, w1h[j * 10 + q]);
            f16x2 wb = __builtin_bit_cast(f16x2, w1h[(j + 1) * 10 + q]);
            s0  = __builtin_amdgcn_fdot2(fh[q], wa, s0, false);
            s1v = __builtin_amdgcn_fdot2(fh[q], wb, s1v, false);
        }
        s0  = fmaxf(s0, 0.01f * s0);
        s1v = fmaxf(s1v, 0.01f * s1v);
        hh[j >> 1] = pkrtz(s0, s1v);
    }

#pragma unroll
    for (int q = 0; q < 32; ++q) {
        f16x2 hv = hh[q];
#pragma unroll
        for (int o = 0; o < 7; ++o)
            acc[o] = __builtin_amdgcn_fdot2(hv, __builtin_bit_cast(f16x2, w2h[o * 32 + q]), acc[o], false);
    }

    float* op = out + (size_t)orig * 7;
#pragma unroll
    for (int o = 0; o < 7; ++o) op[o] = acc[o];
}

extern "C" void kernel_launch(void* const* d_in, const int* in_sizes, int n_in,
                              void* d_out, int out_size, void* d_ws, size_t ws_size,
                              hipStream_t stream) {
    const float* x  = (const float*)d_in[0];
    const float* g0 = (const float*)d_in[1];
    const float* g1 = (const float*)d_in[2];
    const float* g2 = (const float*)d_in[3];
    const float* n0 = (const float*)d_in[4];
    const float* n1 = (const float*)d_in[5];
    const float* n2 = (const float*)d_in[6];
    const float* w1 = (const float*)d_in[7];
    const float* b1 = (const float*)d_in[8];
    const float* w2 = (const float*)d_in[9];
    const float* b2 = (const float*)d_in[10];
    float* out = (float*)d_out;

    const int npts = in_sizes[0] / 3;

    char* ws = (char*)d_ws;
    size_t cur = 0;
    auto alloc = [&](size_t bytes) {
        char* p = ws + cur;
        cur = (cur + bytes + 255) & ~(size_t)255;
        return p;
    };
    float*    p0       = (float*)   alloc(32768u   * 4 * 4 + 64);
    float*    p1       = (float*)   alloc(262144u  * 4 * 4 + 64);
    float*    p2       = (float*)   alloc(2097152u * 2 * 4 + 64);
    unsigned* w1h      = (unsigned*)alloc(640 * 4);
    unsigned* w2h      = (unsigned*)alloc(224 * 4);
    int*      hist     = (int*)     alloc(NBINS * 4);
    int*      offs     = (int*)     alloc(NBINS * 4);
    int*      partials = (int*)     alloc(128 * 4);
    int*      top      = (int*)     alloc(128 * 4);
    float4*   sorted   = (float4*)  alloc((size_t)npts * 16);
    const int useSorted = (ws_size >= cur) ? 1 : 0;

    const int nblk = (npts + 255) / 256;

    (void)hipMemsetAsync(hist, 0, NBINS * 4, stream);
    prep_k<<<PREP_BLOCKS, 256, 0, stream>>>(x, g0, n0, g1, n1, g2, n2, w1, w2,
                                            p0, p1, p2, w1h, w2h, hist, npts);
    if (useSorted) {
        scan_part_k<<<128, 256, 0, stream>>>(hist, partials);
        scan_top_k<<<1, 128, 0, stream>>>(partials, top);
        scan_down_k<<<128, 256, 0, stream>>>(hist, top, offs);
        scatter_k<<<nblk, 256, 0, stream>>>(x, offs, sorted, npts);
    }

    motion_grid_main<<<nblk, 256, 0, stream>>>(
        sorted, x, p0, p1, p2, w1h, b1, w2h, b2, out, npts, useSorted, nblk);
}

// Round 7
// 258.264 us; speedup vs baseline: 9.1546x; 1.7280x over previous
//
#include <hip/hip_runtime.h>

// ---------------------------------------------------------------------------
// Motion_Grid: PE(sin/cos @ 3 freqs) -> 6 trilinear samples (3 grids) -> MLP
// Round 7: ATOMIC-FREE bucket sort. Rounds 3-6 carried ~210us of device-scope
// atomicAdd cost (2M in hist + 2M in scatter; per-XCD L2s aren't coherent so
// device atomics resolve at the slow coherent point). Replaced with radix-style
// per-block LDS counting -> linear scan of counts[bin][blk] -> LDS-ranked
// scatter. Bins 16^3 (fits LDS count array), blocks own contiguous chunks.
// ---------------------------------------------------------------------------

#define NB 4096      // 16^3 bins over raw x in [0,1)^3
#define KB 128       // counting blocks (1024 threads, contiguous point chunk)
#define NXCD 8

typedef _Float16 f16x2 __attribute__((ext_vector_type(2)));

__device__ __forceinline__ f16x2 pkrtz(float a, float b) {
    return __builtin_bit_cast(f16x2, __builtin_amdgcn_cvt_pkrtz(a, b));
}

__device__ __forceinline__ int bin_of(float xv, float yv, float zv) {
    int qx = min(max((int)(xv * 16.f), 0), 15);
    int qy = min(max((int)(yv * 16.f), 0), 15);
    int qz = min(max((int)(zv * 16.f), 0), 15);
    return (qz << 8) | (qy << 4) | qx;
}

// ---- Fused prep: pack g2 | pack g1 | pack g0 | pack weights ----------------
//   [0, 8192)        : pack grid2 (2 ch, 128^3)
//   [8192, 9216)     : pack grid1 (4 ch, 64^3)
//   [9216, 9344)     : pack grid0 (4 ch, 32^3)
//   [9344, 9348)     : pack w1/w2 -> f16-pair tables
#define PREP_BLOCKS 9348

__global__ __launch_bounds__(256)
void prep_k(const float* __restrict__ g0, const float* __restrict__ n0,
            const float* __restrict__ g1, const float* __restrict__ n1,
            const float* __restrict__ g2, const float* __restrict__ n2,
            const float* __restrict__ w1, const float* __restrict__ w2,
            float* __restrict__ p0, float* __restrict__ p1, float* __restrict__ p2,
            unsigned* __restrict__ w1h, unsigned* __restrict__ w2h) {
    const int b = blockIdx.x, t = threadIdx.x;
    if (b < 8192) {                      // pack grid2: nvox = 2097152, C=2
        int v = b * 256 + t;
        float a = g2[v] + n2[v];
        float c = g2[2097152 + v] + n2[2097152 + v];
        reinterpret_cast<float2*>(p2)[v] = make_float2(a, c);
    } else if (b < 9216) {               // pack grid1: nvox = 262144, C=4
        int v = (b - 8192) * 256 + t;
        float4 r;
        r.x = g1[v] + n1[v];
        r.y = g1[262144 + v] + n1[262144 + v];
        r.z = g1[524288 + v] + n1[524288 + v];
        r.w = g1[786432 + v] + n1[786432 + v];
        reinterpret_cast<float4*>(p1)[v] = r;
    } else if (b < 9344) {               // pack grid0: nvox = 32768, C=4
        int v = (b - 9216) * 256 + t;
        float4 r;
        r.x = g0[v] + n0[v];
        r.y = g0[32768 + v] + n0[32768 + v];
        r.z = g0[65536 + v] + n0[65536 + v];
        r.w = g0[98304 + v] + n0[98304 + v];
        reinterpret_cast<float4*>(p0)[v] = r;
    } else {                             // pack weights: 640 + 224 items
        int i = (b - 9344) * 256 + t;
        if (i < 640) {
            int j = i / 10, q = i % 10;
            w1h[i] = __builtin_bit_cast(unsigned, pkrtz(w1[j * 20 + 2 * q], w1[j * 20 + 2 * q + 1]));
        } else if (i < 864) {
            int k = i - 640;
            int o = k / 32, q = k % 32;
            w2h[k] = __builtin_bit_cast(unsigned, pkrtz(w2[o * 64 + 2 * q], w2[o * 64 + 2 * q + 1]));
        }
    }
}

// ---- Atomic-free counting: per-block LDS hist -> counts[bin*KB + blk] ------
__global__ __launch_bounds__(1024)
void count_k(const float* __restrict__ x, int* __restrict__ counts, int npts) {
    __shared__ int h[NB];
    const int t = threadIdx.x, b = blockIdx.x;
    for (int i = t; i < NB; i += 1024) h[i] = 0;
    __syncthreads();
    const int chunk = (npts + KB - 1) / KB;
    const int s = b * chunk, e = min(s + chunk, npts);
    for (int p = s + t; p < e; p += 1024)
        atomicAdd(&h[bin_of(x[3 * p], x[3 * p + 1], x[3 * p + 2])], 1);  // LDS atomic
    __syncthreads();
    for (int i = t; i < NB; i += 1024) counts[i * KB + b] = h[i];
}

// ---- 3-stage exclusive scan over NB*KB = 524288 = 2048*256 elements --------
__global__ __launch_bounds__(256)
void scan_part_k(const int* __restrict__ v_in, int* __restrict__ partials) {
    __shared__ int red[4];
    int t = threadIdx.x, b = blockIdx.x;
    int v = v_in[b * 256 + t];
#pragma unroll
    for (int d = 1; d < 64; d <<= 1) v += __shfl_xor(v, d);
    if ((t & 63) == 0) red[t >> 6] = v;
    __syncthreads();
    if (t == 0) partials[b] = red[0] + red[1] + red[2] + red[3];
}

// Scan 2048 partials with one 1024-thread block (2 elems/thread).
__global__ __launch_bounds__(1024)
void scan_top_k(const int* __restrict__ partials, int* __restrict__ top) {
    __shared__ int sh[1024];
    int t = threadIdx.x;
    int a = partials[2 * t], b = partials[2 * t + 1];
    int s = a + b;
    sh[t] = s;
    __syncthreads();
    for (int d = 1; d < 1024; d <<= 1) {
        int add = (t >= d) ? sh[t - d] : 0;
        __syncthreads();
        sh[t] += add;
        __syncthreads();
    }
    int excl = sh[t] - s;
    top[2 * t] = excl;
    top[2 * t + 1] = excl + a;
}

__global__ __launch_bounds__(256)
void scan_down_k(const int* __restrict__ v_in, const int* __restrict__ top,
                 int* __restrict__ offs) {
    __shared__ int sh[256];
    int t = threadIdx.x, b = blockIdx.x;
    int v = v_in[b * 256 + t];
    sh[t] = v;
    __syncthreads();
    for (int d = 1; d < 256; d <<= 1) {
        int add = (t >= d) ? sh[t - d] : 0;
        __syncthreads();
        sh[t] += add;
        __syncthreads();
    }
    offs[b * 256 + t] = sh[t] - v + top[b];
}

// ---- Scatter: LDS-ranked, no global atomics --------------------------------
__global__ __launch_bounds__(1024)
void scatter_k(const float* __restrict__ x, const int* __restrict__ offs,
               float4* __restrict__ sorted, int npts) {
    __shared__ int base[NB];
    const int t = threadIdx.x, b = blockIdx.x;
    for (int i = t; i < NB; i += 1024) base[i] = offs[i * KB + b];
    __syncthreads();
    const int chunk = (npts + KB - 1) / KB;
    const int s = b * chunk, e = min(s + chunk, npts);
    for (int p = s + t; p < e; p += 1024) {
        float xv = x[3 * p], yv = x[3 * p + 1], zv = x[3 * p + 2];
        int pos = atomicAdd(&base[bin_of(xv, yv, zv)], 1);  // LDS atomic
        float4 v; v.x = xv; v.y = yv; v.z = zv; v.w = __int_as_float(p);
        sorted[pos] = v;
    }
}

// Trilinear sample, border-zero semantics, channel-innermost vol, fused x-pair.
template<int C, int S>
__device__ __forceinline__ void trilerp(const float* __restrict__ vol,
                                        float cx, float cy, float cz,
                                        float* __restrict__ f) {
    const float hs = (float)S * 0.5f;
    float gx = fmaf(cx, hs, hs - 0.5f);
    float gy = fmaf(cy, hs, hs - 0.5f);
    float gz = fmaf(cz, hs, hs - 0.5f);
    float fx = floorf(gx), fy = floorf(gy), fz = floorf(gz);
    float tx = gx - fx, ty = gy - fy, tz = gz - fz;
    int x0 = (int)fx, y0 = (int)fy, z0 = (int)fz;
    float wx0 = (1.f - tx) * ((x0 >= 0)    ? 1.f : 0.f);
    float wx1 = tx         * ((x0 + 1 < S) ? 1.f : 0.f);
    float wy0 = (1.f - ty) * ((y0 >= 0)    ? 1.f : 0.f);
    float wy1 = ty         * ((y0 + 1 < S) ? 1.f : 0.f);
    float wz0 = (1.f - tz) * ((z0 >= 0)    ? 1.f : 0.f);
    float wz1 = tz         * ((z0 + 1 < S) ? 1.f : 0.f);

    const int xb = max(x0, 0);
    const bool xlo_ok = (x0 >= 0);
    int ys[2], zs[2];
    ys[0] = max(y0, 0); ys[1] = min(y0 + 1, S - 1);
    zs[0] = max(z0, 0); zs[1] = min(z0 + 1, S - 1);
    float wys[2] = {wy0, wy1}, wzs[2] = {wz0, wz1};

#pragma unroll
    for (int dz = 0; dz < 2; ++dz) {
#pragma unroll
        for (int dy = 0; dy < 2; ++dy) {
            const float wzy = wzs[dz] * wys[dy];
            const float w0 = wzy * wx0, w1 = wzy * wx1;
            const float* p = vol + ((zs[dz] * S + ys[dy]) * S + xb) * C;
            if (C == 4) {
                float4 lo = *reinterpret_cast<const float4*>(p);
                float4 hi = *reinterpret_cast<const float4*>(p + 4);
                if (!xlo_ok) hi = lo;
                f[0] = fmaf(w0, lo.x, f[0]); f[0] = fmaf(w1, hi.x, f[0]);
                f[1] = fmaf(w0, lo.y, f[1]); f[1] = fmaf(w1, hi.y, f[1]);
                f[2] = fmaf(w0, lo.z, f[2]); f[2] = fmaf(w1, hi.z, f[2]);
                f[3] = fmaf(w0, lo.w, f[3]); f[3] = fmaf(w1, hi.w, f[3]);
            } else {
                float4 v = *reinterpret_cast<const float4*>(p);
                float hx = xlo_ok ? v.z : v.x;
                float hy = xlo_ok ? v.w : v.y;
                f[0] = fmaf(w0, v.x, f[0]); f[0] = fmaf(w1, hx, f[0]);
                f[1] = fmaf(w0, v.y, f[1]); f[1] = fmaf(w1, hy, f[1]);
            }
        }
    }
}

__global__ __launch_bounds__(256)
void motion_grid_main(const float4* __restrict__ sorted,
                      const float* __restrict__ xraw,
                      const float* __restrict__ g0,
                      const float* __restrict__ g1,
                      const float* __restrict__ g2,
                      const unsigned* __restrict__ w1h,
                      const float* __restrict__ b1,
                      const unsigned* __restrict__ w2h,
                      const float* __restrict__ b2,
                      float* __restrict__ out, int npts, int sortedMode,
                      int nblk) {
    // Chunked XCD swizzle: each XCD gets a contiguous run of sorted blocks.
    int bid = blockIdx.x;
    if ((nblk & (NXCD - 1)) == 0) {
        int cpx = nblk / NXCD;
        bid = (bid % NXCD) * cpx + bid / NXCD;
    }
    const int p = bid * 256 + threadIdx.x;
    if (p >= npts) return;

    float xv, yv, zv;
    int orig;
    if (sortedMode) {
        float4 sp = sorted[p];
        xv = sp.x; yv = sp.y; zv = sp.z; orig = __float_as_int(sp.w);
    } else {
        xv = xraw[3 * p]; yv = xraw[3 * p + 1]; zv = xraw[3 * p + 2];
        orig = p;
    }

    // hw trig takes revolutions: sin(pi t)=hw(t/2), sin(2pi t)=hw(t), sin(4pi t)=hw(2t)
    float s1[3], c1[3], s2[3], c2[3], s4[3], c4[3];
    {
        const float xs[3] = {xv, yv, zv};
#pragma unroll
        for (int d = 0; d < 3; ++d) {
            s1[d] = __builtin_amdgcn_sinf(0.5f * xs[d]);
            c1[d] = __builtin_amdgcn_cosf(0.5f * xs[d]);
            s2[d] = __builtin_amdgcn_sinf(xs[d]);
            c2[d] = __builtin_amdgcn_cosf(xs[d]);
            s4[d] = __builtin_amdgcn_sinf(2.0f * xs[d]);
            c4[d] = __builtin_amdgcn_cosf(2.0f * xs[d]);
        }
    }

    float f[20];
#pragma unroll
    for (int i = 0; i < 20; ++i) f[i] = 0.f;

    trilerp<4, 32>(g0, s1[0], s1[1], s1[2], f + 0);
    trilerp<4, 32>(g0, c1[0], c1[1], c1[2], f + 4);
    trilerp<4, 64>(g1, s2[0], s2[1], s2[2], f + 8);
    trilerp<4, 64>(g1, c2[0], c2[1], c2[2], f + 12);
    trilerp<2, 128>(g2, s4[0], s4[1], s4[2], f + 16);
    trilerp<2, 128>(g2, c4[0], c4[1], c4[2], f + 18);

    float acc[7];
#pragma unroll
    for (int o = 0; o < 7; ++o) acc[o] = b2[o];

    // f16-pair dot-product MLP, ALL loops fully unrolled (rule #20: runtime-
    // indexed ext_vector arrays spill to scratch — cost 10x in round 5).
    f16x2 fh[10];
#pragma unroll
    for (int i = 0; i < 10; ++i) fh[i] = pkrtz(f[2 * i], f[2 * i + 1]);

    f16x2 hh[32];
#pragma unroll
    for (int j = 0; j < 64; j += 2) {
        float s0 = b1[j], s1v = b1[j + 1];
#pragma unroll
        for (int q = 0; q < 10; ++q) {
            f16x2 wa = __builtin_bit_cast(f16x2, w1h[j * 10 + q]);
            f16x2 wb = __builtin_bit_cast(f16x2, w1h[(j + 1) * 10 + q]);
            s0  = __builtin_amdgcn_fdot2(fh[q], wa, s0, false);
            s1v = __builtin_amdgcn_fdot2(fh[q], wb, s1v, false);
        }
        s0  = fmaxf(s0, 0.01f * s0);
        s1v = fmaxf(s1v, 0.01f * s1v);
        hh[j >> 1] = pkrtz(s0, s1v);
    }

#pragma unroll
    for (int q = 0; q < 32; ++q) {
        f16x2 hv = hh[q];
#pragma unroll
        for (int o = 0; o < 7; ++o)
            acc[o] = __builtin_amdgcn_fdot2(hv, __builtin_bit_cast(f16x2, w2h[o * 32 + q]), acc[o], false);
    }

    float* op = out + (size_t)orig * 7;
#pragma unroll
    for (int o = 0; o < 7; ++o) op[o] = acc[o];
}

extern "C" void kernel_launch(void* const* d_in, const int* in_sizes, int n_in,
                              void* d_out, int out_size, void* d_ws, size_t ws_size,
                              hipStream_t stream) {
    const float* x  = (const float*)d_in[0];
    const float* g0 = (const float*)d_in[1];
    const float* g1 = (const float*)d_in[2];
    const float* g2 = (const float*)d_in[3];
    const float* n0 = (const float*)d_in[4];
    const float* n1 = (const float*)d_in[5];
    const float* n2 = (const float*)d_in[6];
    const float* w1 = (const float*)d_in[7];
    const float* b1 = (const float*)d_in[8];
    const float* w2 = (const float*)d_in[9];
    const float* b2 = (const float*)d_in[10];
    float* out = (float*)d_out;

    const int npts = in_sizes[0] / 3;

    char* ws = (char*)d_ws;
    size_t cur = 0;
    auto alloc = [&](size_t bytes) {
        char* p = ws + cur;
        cur = (cur + bytes + 255) & ~(size_t)255;
        return p;
    };
    float*    p0       = (float*)   alloc(32768u   * 4 * 4 + 64);
    float*    p1       = (float*)   alloc(262144u  * 4 * 4 + 64);
    float*    p2       = (float*)   alloc(2097152u * 2 * 4 + 64);
    unsigned* w1h      = (unsigned*)alloc(640 * 4);
    unsigned* w2h      = (unsigned*)alloc(224 * 4);
    int*      counts   = (int*)     alloc((size_t)NB * KB * 4);
    int*      offs     = (int*)     alloc((size_t)NB * KB * 4);
    int*      partials = (int*)     alloc(2048 * 4);
    int*      top      = (int*)     alloc(2048 * 4);
    float4*   sorted   = (float4*)  alloc((size_t)npts * 16);
    const int useSorted = (ws_size >= cur) ? 1 : 0;

    const int nblk = (npts + 255) / 256;

    prep_k<<<PREP_BLOCKS, 256, 0, stream>>>(g0, n0, g1, n1, g2, n2, w1, w2,
                                            p0, p1, p2, w1h, w2h);
    if (useSorted) {
        count_k<<<KB, 1024, 0, stream>>>(x, counts, npts);
        scan_part_k<<<(NB * KB) / 256, 256, 0, stream>>>(counts, partials);
        scan_top_k<<<1, 1024, 0, stream>>>(partials, top);
        scan_down_k<<<(NB * KB) / 256, 256, 0, stream>>>(counts, top, offs);
        scatter_k<<<KB, 1024, 0, stream>>>(x, offs, sorted, npts);
    }

    motion_grid_main<<<nblk, 256, 0, stream>>>(
        sorted, x, p0, p1, p2, w1h, b1, w2h, b2, out, npts, useSorted, nblk);
}

// Round 8
// 236.160 us; speedup vs baseline: 10.0115x; 1.0936x over previous
//
#include <hip/hip_runtime.h>

// ---------------------------------------------------------------------------
// Motion_Grid: PE(sin/cos @ 3 freqs) -> 6 trilinear samples (3 grids) -> MLP
// Round 8: f16-packed grids + v_dot2_f32_f16 trilerp (half gather bytes, f32
// accumulation), finer-in-x bins (32x16x16), 256 count/scatter blocks.
// Sort stays atomic-free (round 7 win: device atomics cost ~210us).
// ---------------------------------------------------------------------------

#define NB 8192      // 32x16x16 bins over raw x in [0,1)^3 (finer in x = line dim)
#define KB 256       // counting/scatter blocks (1024 thr, contiguous chunk)
#define NXCD 8

typedef _Float16 f16x2 __attribute__((ext_vector_type(2)));

__device__ __forceinline__ f16x2 pkrtz(float a, float b) {
    return __builtin_bit_cast(f16x2, __builtin_amdgcn_cvt_pkrtz(a, b));
}
__device__ __forceinline__ float fdot2(f16x2 a, f16x2 b, float c) {
    return __builtin_amdgcn_fdot2(a, b, c, false);
}
__device__ __forceinline__ f16x2 u2h(unsigned u) { return __builtin_bit_cast(f16x2, u); }

__device__ __forceinline__ int bin_of(float xv, float yv, float zv) {
    int qx = min(max((int)(xv * 32.f), 0), 31);
    int qy = min(max((int)(yv * 16.f), 0), 15);
    int qz = min(max((int)(zv * 16.f), 0), 15);
    return (qz << 9) | (qy << 5) | qx;
}

// ---- Fused prep: pack grids to f16 [z][y][x][c] + weights to f16 pairs -----
//   [0, 8192)      : grid2 (2 ch, 128^3) -> 4B/voxel
//   [8192, 9216)   : grid1 (4 ch, 64^3)  -> 8B/voxel
//   [9216, 9344)   : grid0 (4 ch, 32^3)  -> 8B/voxel
//   [9344, 9348)   : w1/w2 -> f16-pair tables
#define PREP_BLOCKS 9348

__global__ __launch_bounds__(256)
void prep_k(const float* __restrict__ g0, const float* __restrict__ n0,
            const float* __restrict__ g1, const float* __restrict__ n1,
            const float* __restrict__ g2, const float* __restrict__ n2,
            const float* __restrict__ w1, const float* __restrict__ w2,
            uint2* __restrict__ p0, uint2* __restrict__ p1,
            unsigned* __restrict__ p2,
            unsigned* __restrict__ w1h, unsigned* __restrict__ w2h) {
    const int b = blockIdx.x, t = threadIdx.x;
    if (b < 8192) {                      // grid2: nvox = 2097152, C=2
        int v = b * 256 + t;
        float a = g2[v] + n2[v];
        float c = g2[2097152 + v] + n2[2097152 + v];
        p2[v] = __builtin_bit_cast(unsigned, pkrtz(a, c));
    } else if (b < 9216) {               // grid1: nvox = 262144, C=4
        int v = (b - 8192) * 256 + t;
        float c0 = g1[v] + n1[v];
        float c1 = g1[262144 + v] + n1[262144 + v];
        float c2 = g1[524288 + v] + n1[524288 + v];
        float c3 = g1[786432 + v] + n1[786432 + v];
        uint2 r;
        r.x = __builtin_bit_cast(unsigned, pkrtz(c0, c1));
        r.y = __builtin_bit_cast(unsigned, pkrtz(c2, c3));
        p1[v] = r;
    } else if (b < 9344) {               // grid0: nvox = 32768, C=4
        int v = (b - 9216) * 256 + t;
        float c0 = g0[v] + n0[v];
        float c1 = g0[32768 + v] + n0[32768 + v];
        float c2 = g0[65536 + v] + n0[65536 + v];
        float c3 = g0[98304 + v] + n0[98304 + v];
        uint2 r;
        r.x = __builtin_bit_cast(unsigned, pkrtz(c0, c1));
        r.y = __builtin_bit_cast(unsigned, pkrtz(c2, c3));
        p0[v] = r;
    } else {                             // weights: 640 + 224 items
        int i = (b - 9344) * 256 + t;
        if (i < 640) {
            int j = i / 10, q = i % 10;
            w1h[i] = __builtin_bit_cast(unsigned, pkrtz(w1[j * 20 + 2 * q], w1[j * 20 + 2 * q + 1]));
        } else if (i < 864) {
            int k = i - 640;
            int o = k / 32, q = k % 32;
            w2h[k] = __builtin_bit_cast(unsigned, pkrtz(w2[o * 64 + 2 * q], w2[o * 64 + 2 * q + 1]));
        }
    }
}

// ---- Atomic-free counting: per-block LDS hist -> counts[bin*KB + blk] ------
__global__ __launch_bounds__(1024)
void count_k(const float* __restrict__ x, int* __restrict__ counts, int npts) {
    __shared__ int h[NB];
    const int t = threadIdx.x, b = blockIdx.x;
    for (int i = t; i < NB; i += 1024) h[i] = 0;
    __syncthreads();
    const int chunk = (npts + KB - 1) / KB;
    const int s = b * chunk, e = min(s + chunk, npts);
    for (int p = s + t; p < e; p += 1024)
        atomicAdd(&h[bin_of(x[3 * p], x[3 * p + 1], x[3 * p + 2])], 1);  // LDS atomic
    __syncthreads();
    for (int i = t; i < NB; i += 1024) counts[i * KB + b] = h[i];
}

// ---- 3-stage exclusive scan over NB*KB = 2097152 = 8192*256 elements -------
__global__ __launch_bounds__(256)
void scan_part_k(const int* __restrict__ v_in, int* __restrict__ partials) {
    __shared__ int red[4];
    int t = threadIdx.x, b = blockIdx.x;
    int v = v_in[b * 256 + t];
#pragma unroll
    for (int d = 1; d < 64; d <<= 1) v += __shfl_xor(v, d);
    if ((t & 63) == 0) red[t >> 6] = v;
    __syncthreads();
    if (t == 0) partials[b] = red[0] + red[1] + red[2] + red[3];
}

// Scan 8192 partials: one 1024-thread block, 8 elems/thread.
__global__ __launch_bounds__(1024)
void scan_top_k(const int* __restrict__ partials, int* __restrict__ top) {
    __shared__ int sh[1024];
    int t = threadIdx.x;
    int v[8];
    int s = 0;
#pragma unroll
    for (int i = 0; i < 8; ++i) { v[i] = partials[t * 8 + i]; s += v[i]; }
    sh[t] = s;
    __syncthreads();
    for (int d = 1; d < 1024; d <<= 1) {
        int add = (t >= d) ? sh[t - d] : 0;
        __syncthreads();
        sh[t] += add;
        __syncthreads();
    }
    int run = sh[t] - s;
#pragma unroll
    for (int i = 0; i < 8; ++i) { top[t * 8 + i] = run; run += v[i]; }
}

__global__ __launch_bounds__(256)
void scan_down_k(const int* __restrict__ v_in, const int* __restrict__ top,
                 int* __restrict__ offs) {
    __shared__ int sh[256];
    int t = threadIdx.x, b = blockIdx.x;
    int v = v_in[b * 256 + t];
    sh[t] = v;
    __syncthreads();
    for (int d = 1; d < 256; d <<= 1) {
        int add = (t >= d) ? sh[t - d] : 0;
        __syncthreads();
        sh[t] += add;
        __syncthreads();
    }
    offs[b * 256 + t] = sh[t] - v + top[b];
}

// ---- Scatter: LDS-ranked, no global atomics --------------------------------
__global__ __launch_bounds__(1024)
void scatter_k(const float* __restrict__ x, const int* __restrict__ offs,
               float4* __restrict__ sorted, int npts) {
    __shared__ int base[NB];
    const int t = threadIdx.x, b = blockIdx.x;
    for (int i = t; i < NB; i += 1024) base[i] = offs[i * KB + b];
    __syncthreads();
    const int chunk = (npts + KB - 1) / KB;
    const int s = b * chunk, e = min(s + chunk, npts);
    for (int p = s + t; p < e; p += 1024) {
        float xv = x[3 * p], yv = x[3 * p + 1], zv = x[3 * p + 2];
        int pos = atomicAdd(&base[bin_of(xv, yv, zv)], 1);  // LDS atomic
        float4 v; v.x = xv; v.y = yv; v.z = zv; v.w = __int_as_float(p);
        sorted[pos] = v;
    }
}

// ---- f16 trilinear, f32 accumulation via v_dot2_f32_f16 --------------------
// Per (z,y) row: one fused x-pair load, per-channel (lo,hi) pair via
// v_perm_b32, weight pair (wzy*wx0, wzy*wx1) via cvt_pkrtz + v_pk_mul_f16.
template<int S>
__device__ __forceinline__ void setup_coords(float cx, float cy, float cz,
                                             int& xb, bool& xlo_ok, f16x2& wx2,
                                             int* ys, int* zs, float* wys, float* wzs) {
    const float hs = (float)S * 0.5f;
    float gx = fmaf(cx, hs, hs - 0.5f);
    float gy = fmaf(cy, hs, hs - 0.5f);
    float gz = fmaf(cz, hs, hs - 0.5f);
    float fx = floorf(gx), fy = floorf(gy), fz = floorf(gz);
    float tx = gx - fx, ty = gy - fy, tz = gz - fz;
    int x0 = (int)fx, y0 = (int)fy, z0 = (int)fz;
    float wx0 = (1.f - tx) * ((x0 >= 0)    ? 1.f : 0.f);
    float wx1 = tx         * ((x0 + 1 < S) ? 1.f : 0.f);
    wys[0] = (1.f - ty) * ((y0 >= 0)    ? 1.f : 0.f);
    wys[1] = ty         * ((y0 + 1 < S) ? 1.f : 0.f);
    wzs[0] = (1.f - tz) * ((z0 >= 0)    ? 1.f : 0.f);
    wzs[1] = tz         * ((z0 + 1 < S) ? 1.f : 0.f);
    xb = max(x0, 0);
    xlo_ok = (x0 >= 0);
    wx2 = pkrtz(wx0, wx1);
    ys[0] = max(y0, 0); ys[1] = min(y0 + 1, S - 1);
    zs[0] = max(z0, 0); zs[1] = min(z0 + 1, S - 1);
}

template<int S>
__device__ __forceinline__ void trilerp4h(const uint2* __restrict__ vol,
                                          float cx, float cy, float cz,
                                          float* __restrict__ f) {
    int xb, ys[2], zs[2];
    bool xlo_ok;
    f16x2 wx2;
    float wys[2], wzs[2];
    setup_coords<S>(cx, cy, cz, xb, xlo_ok, wx2, ys, zs, wys, wzs);

#pragma unroll
    for (int dz = 0; dz < 2; ++dz) {
#pragma unroll
        for (int dy = 0; dy < 2; ++dy) {
            const float wzy = wzs[dz] * wys[dy];
            f16x2 wp = pkrtz(wzy, wzy) * wx2;           // (wzy*wx0, wzy*wx1)
            const uint2* p = vol + (zs[dz] * S + ys[dy]) * S + xb;
            uint2 lo = p[0];
            uint2 hi = p[1];                            // 8B past row-end has weight 0
            if (!xlo_ok) hi = lo;                       // clamped-left: corner1 = index 0
            unsigned pc0 = __builtin_amdgcn_perm(hi.x, lo.x, 0x05040100u);  // (lo_c0,hi_c0)
            unsigned pc1 = __builtin_amdgcn_perm(hi.x, lo.x, 0x07060302u);  // (lo_c1,hi_c1)
            unsigned pc2 = __builtin_amdgcn_perm(hi.y, lo.y, 0x05040100u);
            unsigned pc3 = __builtin_amdgcn_perm(hi.y, lo.y, 0x07060302u);
            f[0] = fdot2(wp, u2h(pc0), f[0]);
            f[1] = fdot2(wp, u2h(pc1), f[1]);
            f[2] = fdot2(wp, u2h(pc2), f[2]);
            f[3] = fdot2(wp, u2h(pc3), f[3]);
        }
    }
}

template<int S>
__device__ __forceinline__ void trilerp2h(const unsigned* __restrict__ vol,
                                          float cx, float cy, float cz,
                                          float* __restrict__ f) {
    int xb, ys[2], zs[2];
    bool xlo_ok;
    f16x2 wx2;
    float wys[2], wzs[2];
    setup_coords<S>(cx, cy, cz, xb, xlo_ok, wx2, ys, zs, wys, wzs);

#pragma unroll
    for (int dz = 0; dz < 2; ++dz) {
#pragma unroll
        for (int dy = 0; dy < 2; ++dy) {
            const float wzy = wzs[dz] * wys[dy];
            f16x2 wp = pkrtz(wzy, wzy) * wx2;
            const unsigned* p = vol + (zs[dz] * S + ys[dy]) * S + xb;
            unsigned lo = p[0];
            unsigned hi = p[1];
            if (!xlo_ok) hi = lo;
            unsigned pc0 = __builtin_amdgcn_perm(hi, lo, 0x05040100u);
            unsigned pc1 = __builtin_amdgcn_perm(hi, lo, 0x07060302u);
            f[0] = fdot2(wp, u2h(pc0), f[0]);
            f[1] = fdot2(wp, u2h(pc1), f[1]);
        }
    }
}

__global__ __launch_bounds__(256)
void motion_grid_main(const float4* __restrict__ sorted,
                      const float* __restrict__ xraw,
                      const uint2* __restrict__ g0,
                      const uint2* __restrict__ g1,
                      const unsigned* __restrict__ g2,
                      const unsigned* __restrict__ w1h,
                      const float* __restrict__ b1,
                      const unsigned* __restrict__ w2h,
                      const float* __restrict__ b2,
                      float* __restrict__ out, int npts, int sortedMode,
                      int nblk) {
    // Chunked XCD swizzle: each XCD gets a contiguous run of sorted blocks.
    int bid = blockIdx.x;
    if ((nblk & (NXCD - 1)) == 0) {
        int cpx = nblk / NXCD;
        bid = (bid % NXCD) * cpx + bid / NXCD;
    }
    const int p = bid * 256 + threadIdx.x;
    if (p >= npts) return;

    float xv, yv, zv;
    int orig;
    if (sortedMode) {
        float4 sp = sorted[p];
        xv = sp.x; yv = sp.y; zv = sp.z; orig = __float_as_int(sp.w);
    } else {
        xv = xraw[3 * p]; yv = xraw[3 * p + 1]; zv = xraw[3 * p + 2];
        orig = p;
    }

    // hw trig takes revolutions: sin(pi t)=hw(t/2), sin(2pi t)=hw(t), sin(4pi t)=hw(2t)
    float s1[3], c1[3], s2[3], c2[3], s4[3], c4[3];
    {
        const float xs[3] = {xv, yv, zv};
#pragma unroll
        for (int d = 0; d < 3; ++d) {
            s1[d] = __builtin_amdgcn_sinf(0.5f * xs[d]);
            c1[d] = __builtin_amdgcn_cosf(0.5f * xs[d]);
            s2[d] = __builtin_amdgcn_sinf(xs[d]);
            c2[d] = __builtin_amdgcn_cosf(xs[d]);
            s4[d] = __builtin_amdgcn_sinf(2.0f * xs[d]);
            c4[d] = __builtin_amdgcn_cosf(2.0f * xs[d]);
        }
    }

    float f[20];
#pragma unroll
    for (int i = 0; i < 20; ++i) f[i] = 0.f;

    trilerp4h<32>(g0, s1[0], s1[1], s1[2], f + 0);
    trilerp4h<32>(g0, c1[0], c1[1], c1[2], f + 4);
    trilerp4h<64>(g1, s2[0], s2[1], s2[2], f + 8);
    trilerp4h<64>(g1, c2[0], c2[1], c2[2], f + 12);
    trilerp2h<128>(g2, s4[0], s4[1], s4[2], f + 16);
    trilerp2h<128>(g2, c4[0], c4[1], c4[2], f + 18);

    float acc[7];
#pragma unroll
    for (int o = 0; o < 7; ++o) acc[o] = b2[o];

    // f16-pair dot-product MLP, ALL loops fully unrolled (rule #20: runtime-
    // indexed ext_vector arrays spill to scratch — cost 10x in round 5).
    f16x2 fh[10];
#pragma unroll
    for (int i = 0; i < 10; ++i) fh[i] = pkrtz(f[2 * i], f[2 * i + 1]);

    f16x2 hh[32];
#pragma unroll
    for (int j = 0; j < 64; j += 2) {
        float s0 = b1[j], s1v = b1[j + 1];
#pragma unroll
        for (int q = 0; q < 10; ++q) {
            f16x2 wa = __builtin_bit_cast(f16x2, w1h[j * 10 + q]);
            f16x2 wb = __builtin_bit_cast(f16x2, w1h[(j + 1) * 10 + q]);
            s0  = fdot2(fh[q], wa, s0);
            s1v = fdot2(fh[q], wb, s1v);
        }
        s0  = fmaxf(s0, 0.01f * s0);
        s1v = fmaxf(s1v, 0.01f * s1v);
        hh[j >> 1] = pkrtz(s0, s1v);
    }

#pragma unroll
    for (int q = 0; q < 32; ++q) {
        f16x2 hv = hh[q];
#pragma unroll
        for (int o = 0; o < 7; ++o)
            acc[o] = fdot2(hv, __builtin_bit_cast(f16x2, w2h[o * 32 + q]), acc[o]);
    }

    float* op = out + (size_t)orig * 7;
#pragma unroll
    for (int o = 0; o < 7; ++o) op[o] = acc[o];
}

extern "C" void kernel_launch(void* const* d_in, const int* in_sizes, int n_in,
                              void* d_out, int out_size, void* d_ws, size_t ws_size,
                              hipStream_t stream) {
    const float* x  = (const float*)d_in[0];
    const float* g0 = (const float*)d_in[1];
    const float* g1 = (const float*)d_in[2];
    const float* g2 = (const float*)d_in[3];
    const float* n0 = (const float*)d_in[4];
    const float* n1 = (const float*)d_in[5];
    const float* n2 = (const float*)d_in[6];
    const float* w1 = (const float*)d_in[7];
    const float* b1 = (const float*)d_in[8];
    const float* w2 = (const float*)d_in[9];
    const float* b2 = (const float*)d_in[10];
    float* out = (float*)d_out;

    const int npts = in_sizes[0] / 3;

    char* ws = (char*)d_ws;
    size_t cur = 0;
    auto alloc = [&](size_t bytes) {
        char* p = ws + cur;
        cur = (cur + bytes + 255) & ~(size_t)255;
        return p;
    };
    uint2*    p0       = (uint2*)   alloc(32768u   * 8 + 64);
    uint2*    p1       = (uint2*)   alloc(262144u  * 8 + 64);
    unsigned* p2       = (unsigned*)alloc(2097152u * 4 + 64);
    unsigned* w1h      = (unsigned*)alloc(640 * 4);
    unsigned* w2h      = (unsigned*)alloc(224 * 4);
    int*      counts   = (int*)     alloc((size_t)NB * KB * 4);
    int*      offs     = (int*)     alloc((size_t)NB * KB * 4);
    int*      partials = (int*)     alloc((size_t)(NB * KB / 256) * 4);
    int*      top      = (int*)     alloc((size_t)(NB * KB / 256) * 4);
    float4*   sorted   = (float4*)  alloc((size_t)npts * 16);
    const int useSorted = (ws_size >= cur) ? 1 : 0;

    const int nblk = (npts + 255) / 256;

    prep_k<<<PREP_BLOCKS, 256, 0, stream>>>(g0, n0, g1, n1, g2, n2, w1, w2,
                                            p0, p1, p2, w1h, w2h);
    if (useSorted) {
        count_k<<<KB, 1024, 0, stream>>>(x, counts, npts);
        scan_part_k<<<(NB * KB) / 256, 256, 0, stream>>>(counts, partials);
        scan_top_k<<<1, 1024, 0, stream>>>(partials, top);
        scan_down_k<<<(NB * KB) / 256, 256, 0, stream>>>(counts, top, offs);
        scatter_k<<<KB, 1024, 0, stream>>>(x, offs, sorted, npts);
    }

    motion_grid_main<<<nblk, 256, 0, stream>>>(
        sorted, x, p0, p1, p2, w1h, b1, w2h, b2, out, npts, useSorted, nblk);
}